// Round 1
// baseline (216.457 us; speedup 1.0000x reference)
//
#include <hip/hip_runtime.h>

// CovarianceLayer: x [B=64, C=4, T=8192, M=16] fp32 -> cov [B, C, 16, 16] fp32
// One-pass co-moment: cov = (P_mn - S_m*S_n/T) / (T-1)
// One block per (b,c); 512 threads; per-thread register accumulators
// (16 sums + 136 upper-triangle products), shuffle-tree + LDS reduction.

constexpr int T_DIM = 8192;
constexpr int M_DIM = 16;
constexpr int NPAIR = 136;               // 16*17/2 upper triangle incl. diag
constexpr int BLOCK = 512;               // 8 waves
constexpr int NACC  = M_DIM + NPAIR;     // 152

__global__ __launch_bounds__(BLOCK, 2)
void cov_kernel(const float* __restrict__ x, float* __restrict__ out) {
    const int bc  = blockIdx.x;          // (b*C + c)
    const int tid = threadIdx.x;
    const float* __restrict__ xin = x + (size_t)bc * (size_t)(T_DIM * M_DIM);

    float s[M_DIM];
    float p[NPAIR];
#pragma unroll
    for (int i = 0; i < M_DIM; ++i) s[i] = 0.0f;
#pragma unroll
    for (int i = 0; i < NPAIR; ++i) p[i] = 0.0f;

    // Main loop: each thread owns rows tid, tid+512, ... (16 rows).
#pragma unroll 2
    for (int it = 0; it < T_DIM / BLOCK; ++it) {
        const int r = tid + it * BLOCK;
        const float4* __restrict__ rp = (const float4*)(xin + r * M_DIM);
        const float4 v0 = rp[0];
        const float4 v1 = rp[1];
        const float4 v2 = rp[2];
        const float4 v3 = rp[3];
        const float row[M_DIM] = {v0.x, v0.y, v0.z, v0.w,
                                  v1.x, v1.y, v1.z, v1.w,
                                  v2.x, v2.y, v2.z, v2.w,
                                  v3.x, v3.y, v3.z, v3.w};
#pragma unroll
        for (int m = 0; m < M_DIM; ++m) s[m] += row[m];
        int idx = 0;
#pragma unroll
        for (int m = 0; m < M_DIM; ++m) {
#pragma unroll
            for (int n = m; n < M_DIM; ++n) {
                p[idx++] += row[m] * row[n];
            }
        }
    }

    // Intra-wave reduction (wave = 64 lanes on CDNA).
#pragma unroll
    for (int off = 32; off > 0; off >>= 1) {
#pragma unroll
        for (int i = 0; i < M_DIM; ++i) s[i] += __shfl_down(s[i], off, 64);
#pragma unroll
        for (int i = 0; i < NPAIR; ++i) p[i] += __shfl_down(p[i], off, 64);
    }

    // Cross-wave reduction via LDS.
    __shared__ float red[BLOCK / 64][NACC];
    __shared__ float tot[NACC];
    const int wave = tid >> 6;
    const int lane = tid & 63;
    if (lane == 0) {
#pragma unroll
        for (int i = 0; i < M_DIM; ++i) red[wave][i] = s[i];
#pragma unroll
        for (int i = 0; i < NPAIR; ++i) red[wave][M_DIM + i] = p[i];
    }
    __syncthreads();
    if (tid < NACC) {
        float a = 0.0f;
#pragma unroll
        for (int w = 0; w < BLOCK / 64; ++w) a += red[w][tid];
        tot[tid] = a;
    }
    __syncthreads();

    // Finalize: cov[m][n] = (P - Sm*Sn/T) / (T-1); full 16x16 (symmetric).
    if (tid < M_DIM * M_DIM) {
        const int m = tid >> 4;
        const int n = tid & 15;
        const int mm = m < n ? m : n;
        const int nn = m < n ? n : m;
        const int idx = mm * M_DIM - (mm * (mm + 1)) / 2 + nn;
        const float Sm = tot[m];
        const float Sn = tot[n];
        const float P  = tot[M_DIM + idx];
        const float cov = (P - Sm * Sn * (1.0f / (float)T_DIM))
                        * (1.0f / (float)(T_DIM - 1));
        out[(size_t)bc * (M_DIM * M_DIM) + tid] = cov;
    }
}

extern "C" void kernel_launch(void* const* d_in, const int* in_sizes, int n_in,
                              void* d_out, int out_size, void* d_ws, size_t ws_size,
                              hipStream_t stream) {
    const float* x = (const float*)d_in[0];
    float* out = (float*)d_out;
    const int n_bc = in_sizes[0] / (T_DIM * M_DIM);   // B*C = 256
    cov_kernel<<<dim3(n_bc), dim3(BLOCK), 0, stream>>>(x, out);
}

// Round 3
// 187.592 us; speedup vs baseline: 1.1539x; 1.1539x over previous
//
#include <hip/hip_runtime.h>

// CovarianceLayer: x [B=64, C=4, T=8192, M=16] fp32 -> cov [B, C, 16, 16] fp32
// cov = (P - S S^T / T) / (T-1),  P = X^T X via mfma_f32_16x16x32_bf16.
//
// Single kernel, one block per (b,c), 16 waves. Each wave accumulates a
// partial P (4 AGPRs/lane) + fp32 column sums over a 512-row slice; block
// combine + finalize in LDS; one coalesced store. No d_ws, no atomics, no
// memsets -> fully deterministic and no scratch-size assumptions (R2's
// post-timing divergence implicated OOB writes through d_ws).
//
// Fragment trick: for P = X^T X the A-fragment (A[m=lane&15][k=quad*8+j])
// and B-fragment (B[k][n=lane&15]) are the same 8 values -> one set of
// loads feeds both operands. bf16 rounding perturbs cov by ~1e-4 max
// (threshold 2.1e-2); column sums stay fp32 so the mean term is exact.

constexpr int T_DIM = 8192;
constexpr int M_DIM = 16;
constexpr int BLOCK = 1024;               // 16 waves
constexpr int NWAVE = BLOCK / 64;         // 16
constexpr int T_PER_WAVE = T_DIM / NWAVE; // 512 rows per wave
constexpr int CHUNKS = T_PER_WAVE / 32;   // 16 MFMA k-chunks per wave

using bf16x8 = __attribute__((ext_vector_type(8))) short;
using f32x4  = __attribute__((ext_vector_type(4))) float;

static __device__ inline short f2bf(float f) {
    // round-to-nearest-even fp32 -> bf16 (inputs are finite normals)
    union { float f; unsigned u; } v{f};
    unsigned r = v.u + 0x7fffu + ((v.u >> 16) & 1u);
    return (short)(r >> 16);
}

__global__ __launch_bounds__(BLOCK)
void cov_kernel(const float* __restrict__ x, float* __restrict__ out) {
    const int bc   = blockIdx.x;
    const int tid  = threadIdx.x;
    const int wave = tid >> 6;
    const int lane = tid & 63;
    const int q    = lane >> 4;    // quad 0..3
    const int m    = lane & 15;    // variable (column) this lane loads

    // lane base: x[bc][wave*512 + q*8 + j][m], j = 0..7 at 64B steps.
    // Lanes m=0..15 of a quad cover one full 64B line -> line-dense loads.
    const int t0 = wave * T_PER_WAVE + q * 8;
    const float* __restrict__ base =
        x + (size_t)bc * (T_DIM * M_DIM) + (size_t)t0 * M_DIM + m;

    f32x4 acc = {0.f, 0.f, 0.f, 0.f};
    float sum = 0.f;

#pragma unroll 2
    for (int c = 0; c < CHUNKS; ++c) {
        const float* __restrict__ p = base + (size_t)c * 32 * M_DIM;
        float f0 = p[0 * M_DIM], f1 = p[1 * M_DIM];
        float f2 = p[2 * M_DIM], f3 = p[3 * M_DIM];
        float f4 = p[4 * M_DIM], f5 = p[5 * M_DIM];
        float f6 = p[6 * M_DIM], f7 = p[7 * M_DIM];
        sum += ((f0 + f1) + (f2 + f3)) + ((f4 + f5) + (f6 + f7));
        bf16x8 frag;
        frag[0] = f2bf(f0); frag[1] = f2bf(f1);
        frag[2] = f2bf(f2); frag[3] = f2bf(f3);
        frag[4] = f2bf(f4); frag[5] = f2bf(f5);
        frag[6] = f2bf(f6); frag[7] = f2bf(f7);
        acc = __builtin_amdgcn_mfma_f32_16x16x32_bf16(frag, frag, acc, 0, 0, 0);
    }

    // Wave column sums: combine the 4 quads -> lane m holds col-m sum.
    sum += __shfl_xor(sum, 16, 64);
    sum += __shfl_xor(sum, 32, 64);

    // Block combine in LDS.
    __shared__ float Pred[NWAVE][256];   // per-wave partial P, [row*16+col]
    __shared__ float Sred[NWAVE][M_DIM];
    __shared__ float Stot[M_DIM];

    // C/D layout: col = lane&15, row = (lane>>4)*4 + reg.
#pragma unroll
    for (int r = 0; r < 4; ++r)
        Pred[wave][(q * 4 + r) * M_DIM + m] = acc[r];
    if (lane < M_DIM) Sred[wave][lane] = sum;
    __syncthreads();

    if (tid < M_DIM) {
        float s = 0.f;
#pragma unroll
        for (int w = 0; w < NWAVE; ++w) s += Sred[w][tid];
        Stot[tid] = s;
    }
    __syncthreads();

    if (tid < 256) {
        float P = 0.f;
#pragma unroll
        for (int w = 0; w < NWAVE; ++w) P += Pred[w][tid];
        const int mi = tid >> 4;
        const int ni = tid & 15;
        const float cov = (P - Stot[mi] * Stot[ni] * (1.0f / (float)T_DIM))
                        * (1.0f / (float)(T_DIM - 1));
        out[(size_t)bc * 256 + tid] = cov;
    }
}

extern "C" void kernel_launch(void* const* d_in, const int* in_sizes, int n_in,
                              void* d_out, int out_size, void* d_ws, size_t ws_size,
                              hipStream_t stream) {
    const float* x = (const float*)d_in[0];
    float* out = (float*)d_out;
    const int n_bc = in_sizes[0] / (T_DIM * M_DIM);   // B*C = 256
    cov_kernel<<<dim3(n_bc), dim3(BLOCK), 0, stream>>>(x, out);
}

// Round 4
// 185.282 us; speedup vs baseline: 1.1683x; 1.0125x over previous
//
#include <hip/hip_runtime.h>

// CovarianceLayer: x [B=64, C=4, T=8192, M=16] fp32 -> cov [B, C, 16, 16] fp32
// cov = (P - S S^T / T) / (T-1),  P = X^T X via mfma_f32_16x16x32_bf16.
//
// R4: vectorized load path. Each wave, per 32-row round:
//   - 2x global float4 loads per lane (coalesced: 16 full 64B lines/instr)
//   - fp32 column sums (exact mean term) from the loaded registers
//   - pack to bf16 pairs, scatter-transpose into a wave-private LDS buffer
//     (granule-swizzled: reads conflict-free, writes 2 lanes/bank = free)
//   - one ds_read_b128 -> bf16x8 fragment (A == B since P = X^T X), 1 MFMA
// No barriers in the main loop (wave-private staging, lgkmcnt only).
// Block-combine + finalize epilogue identical to the verified R3 kernel.

constexpr int T_DIM = 8192;
constexpr int M_DIM = 16;
constexpr int BLOCK = 1024;                 // 16 waves, 1 block per (b,c)
constexpr int NWAVE = BLOCK / 64;           // 16
constexpr int T_PER_WAVE = T_DIM / NWAVE;   // 512 rows
constexpr int ROUNDS = T_PER_WAVE / 32;     // 16 rounds of 32 rows

using bf16x8 = __attribute__((ext_vector_type(8))) short;
using f32x4  = __attribute__((ext_vector_type(4))) float;

static __device__ inline unsigned pack_bf2(float lo, float hi) {
    // RNE fp32->bf16 for both, packed lo | hi<<16 (finite normal inputs)
    union { float f; unsigned u; } a{lo}, b{hi};
    unsigned ra = a.u + 0x7fffu + ((a.u >> 16) & 1u);
    unsigned rb = b.u + 0x7fffu + ((b.u >> 16) & 1u);
    return (ra >> 16) | (rb & 0xffff0000u);
}

__global__ __launch_bounds__(BLOCK)
void cov_kernel(const float* __restrict__ x, float* __restrict__ out) {
    const int bc   = blockIdx.x;
    const int tid  = threadIdx.x;
    const int wave = tid >> 6;
    const int lane = tid & 63;

    // staging roles: lane covers rows 2rg..2rg+1 (round-local), cols 4g..4g+3
    const int rg = lane & 15;
    const int g  = lane >> 4;
    // MFMA roles: col = m, k-rows q*8..q*8+7 (verified layout from R3)
    const int q  = lane >> 4;
    const int m  = lane & 15;

    __shared__ __align__(16) unsigned stage[NWAVE][2][256]; // 2x 1KB per wave
    __shared__ float Pred[NWAVE][256];
    __shared__ float Sred[NWAVE][M_DIM];
    __shared__ float Stot[M_DIM];

    const float4* __restrict__ xin =
        (const float4*)(x + (size_t)bc * (T_DIM * M_DIM));

    // float4 index of (row, segment g) = row*4 + g
    int idx = (wave * T_PER_WAVE + 2 * rg) * 4 + g;

    // LDS write offsets: granule = qw*16 + (col ^ qw), dword-in-granule = dq
    const int qw = rg >> 2, dq = rg & 3;
    // LDS read pointer: granule = q*16 + (m ^ q), 16B each
    const int roff = (q * 16 + (m ^ q)) * 4;

    f32x4 acc = {0.f, 0.f, 0.f, 0.f};
    float s0 = 0.f, s1 = 0.f, s2 = 0.f, s3 = 0.f;

    float4 a0 = xin[idx], a1 = xin[idx + 4];

#define COV_PROCESS(A0, A1, R)                                               \
    do {                                                                     \
        s0 += (A0).x + (A1).x;  s1 += (A0).y + (A1).y;                       \
        s2 += (A0).z + (A1).z;  s3 += (A0).w + (A1).w;                       \
        unsigned* wb = &stage[wave][(R) & 1][0];                             \
        wb[(qw * 16 + ((4 * g + 0) ^ qw)) * 4 + dq] = pack_bf2((A0).x, (A1).x); \
        wb[(qw * 16 + ((4 * g + 1) ^ qw)) * 4 + dq] = pack_bf2((A0).y, (A1).y); \
        wb[(qw * 16 + ((4 * g + 2) ^ qw)) * 4 + dq] = pack_bf2((A0).z, (A1).z); \
        wb[(qw * 16 + ((4 * g + 3) ^ qw)) * 4 + dq] = pack_bf2((A0).w, (A1).w); \
        bf16x8 frag = *(const bf16x8*)&stage[wave][(R) & 1][roff];           \
        acc = __builtin_amdgcn_mfma_f32_16x16x32_bf16(frag, frag, acc, 0, 0, 0); \
    } while (0)

#pragma unroll 4
    for (int r = 0; r < ROUNDS - 1; ++r) {
        const int nidx = idx + 32 * 4;            // next round: +32 rows
        float4 b0 = xin[nidx], b1 = xin[nidx + 4]; // prefetch in flight
        COV_PROCESS(a0, a1, r);
        a0 = b0; a1 = b1; idx = nidx;
    }
    COV_PROCESS(a0, a1, ROUNDS - 1);
#undef COV_PROCESS

    // Wave column sums: reduce over rg (lane bits 0..3); lanes rg==0 hold
    // cols 4g..4g+3.
#pragma unroll
    for (int off = 1; off <= 8; off <<= 1) {
        s0 += __shfl_xor(s0, off, 64);
        s1 += __shfl_xor(s1, off, 64);
        s2 += __shfl_xor(s2, off, 64);
        s3 += __shfl_xor(s3, off, 64);
    }
    if (rg == 0) {
        Sred[wave][4 * g + 0] = s0;
        Sred[wave][4 * g + 1] = s1;
        Sred[wave][4 * g + 2] = s2;
        Sred[wave][4 * g + 3] = s3;
    }

    // Per-wave partial P into LDS. C/D layout: col = m, row = q*4 + reg.
#pragma unroll
    for (int r = 0; r < 4; ++r)
        Pred[wave][(q * 4 + r) * M_DIM + m] = acc[r];
    __syncthreads();

    if (tid < M_DIM) {
        float s = 0.f;
#pragma unroll
        for (int w = 0; w < NWAVE; ++w) s += Sred[w][tid];
        Stot[tid] = s;
    }
    __syncthreads();

    if (tid < 256) {
        float P = 0.f;
#pragma unroll
        for (int w = 0; w < NWAVE; ++w) P += Pred[w][tid];
        const int mi = tid >> 4;
        const int ni = tid & 15;
        const float cov = (P - Stot[mi] * Stot[ni] * (1.0f / (float)T_DIM))
                        * (1.0f / (float)(T_DIM - 1));
        out[(size_t)bc * 256 + tid] = cov;
    }
}

extern "C" void kernel_launch(void* const* d_in, const int* in_sizes, int n_in,
                              void* d_out, int out_size, void* d_ws, size_t ws_size,
                              hipStream_t stream) {
    const float* x = (const float*)d_in[0];
    float* out = (float*)d_out;
    const int n_bc = in_sizes[0] / (T_DIM * M_DIM);   // B*C = 256
    cov_kernel<<<dim3(n_bc), dim3(BLOCK), 0, stream>>>(x, out);
}